// Round 2
// baseline (6438.814 us; speedup 1.0000x reference)
//
#include <hip/hip_runtime.h>
#include <stdint.h>

#define EPS 1e-3f

typedef _Float16 f16x8 __attribute__((ext_vector_type(8)));
typedef float f32x4 __attribute__((ext_vector_type(4)));

// ---------------------------------------------------------------------------
// Setup: fold BN into per-channel scale/bias; prepack w_pos into 8 "slide"
// variants of MFMA A-fragments (f16), transposed taps (r<->s):
//   Apack[off][u][r'][lane][j] = w_pos[kk=lane&15][u][s'= (lane>>4)*8+j-off][r']
//   (zero when s'-index outside [0,23))
// One fragment = 64 lanes x 16 B, contiguous -> coalesced dwordx4 loads.
// ---------------------------------------------------------------------------
__global__ __launch_bounds__(256) void setup_kernel(
    const float* __restrict__ w_pos,
    const float* __restrict__ gq, const float* __restrict__ bq,
    const float* __restrict__ mq, const float* __restrict__ vq,
    const float* __restrict__ gv, const float* __restrict__ bv,
    const float* __restrict__ mv, const float* __restrict__ vvar,
    float* __restrict__ scale_bias, _Float16* __restrict__ Apack) {
  const int idx = blockIdx.x * 256 + threadIdx.x;
  if (idx < 384) {
    float sc, bi;
    if (idx < 64) {
      const float inv = gq[idx] * rsqrtf(vq[idx] + EPS);
      sc = inv; bi = bq[idx] - mq[idx] * inv;
    } else if (idx < 128) {
      sc = 1.f; bi = 0.f;  // k has no BN
    } else {
      const int o = idx - 128;
      const float inv = gv[o] * rsqrtf(vvar[o] + EPS);
      sc = inv; bi = bv[o] - mv[o] * inv;
    }
    scale_bias[idx] = sc;
    scale_bias[384 + idx] = bi;
  }
  if (idx < 376832) {  // 8 off * 4 u * 23 r' * 64 lanes * 8 halfs
    const int j = idx & 7;
    const int lane = (idx >> 3) & 63;
    const int rp = (idx >> 9) % 23;
    const int uo = (idx >> 9) / 23;
    const int u = uo & 3;
    const int off = uo >> 2;
    const int kk = lane & 15;
    const int quad = (lane >> 4) & 3;
    const int sp = quad * 8 + j - off;  // transposed tap: orig r-index
    float val = 0.f;
    if (sp >= 0 && sp < 23)
      val = w_pos[kk * 2116 + u * 529 + sp * 23 + rp];
    Apack[idx] = (_Float16)val;
  }
}

// ---------------------------------------------------------------------------
// Projection GEMM (unchanged from round 1)
// ---------------------------------------------------------------------------
__global__ __launch_bounds__(256) void proj_gemm(
    const float* __restrict__ x,
    const float* __restrict__ w_q, const float* __restrict__ w_k,
    const float* __restrict__ w_v,
    const float* __restrict__ scale_bias,
    float* __restrict__ proj) {
  const int b = blockIdx.z;
  const int ot = blockIdx.y;
  const int nBase = blockIdx.x * 64;
  const int tid = threadIdx.x;
  const int tx = tid & 15, ty = tid >> 4;

  const float* W;
  int oRow;
  if (ot == 0)      { W = w_q; oRow = 0; }
  else if (ot == 1) { W = w_k; oRow = 0; }
  else              { W = w_v; oRow = (ot - 2) * 64; }

  __shared__ float la[32][64];
  __shared__ float lb[32][64];

  float acc[4][4];
#pragma unroll
  for (int i = 0; i < 4; i++)
#pragma unroll
    for (int j = 0; j < 4; j++) acc[i][j] = 0.f;

  const int o_l = tid & 63;
  const int c4a = (tid >> 6) * 4;
  const int cb = tid >> 4;
  const int n4 = (tid & 15) * 4;

  for (int k0 = 0; k0 < 256; k0 += 32) {
    __syncthreads();
#pragma unroll
    for (int rr = 0; rr < 2; rr++) {
      const int c0 = c4a + rr * 16;
      const float4 wv4 = *(const float4*)&W[(size_t)(oRow + o_l) * 256 + k0 + c0];
      la[c0 + 0][o_l] = wv4.x;
      la[c0 + 1][o_l] = wv4.y;
      la[c0 + 2][o_l] = wv4.z;
      la[c0 + 3][o_l] = wv4.w;
    }
#pragma unroll
    for (int rr = 0; rr < 2; rr++) {
      const int c_l = cb + rr * 16;
      const float4 xv =
          *(const float4*)&x[((size_t)(b * 256 + k0 + c_l)) * 4096 + nBase + n4];
      *(float4*)&lb[c_l][n4] = xv;
    }
    __syncthreads();
#pragma unroll
    for (int kk = 0; kk < 32; kk++) {
      const float4 av = *(const float4*)&la[kk][ty * 4];
      const float4 bv = *(const float4*)&lb[kk][tx * 4];
      const float a[4] = {av.x, av.y, av.z, av.w};
      const float bb[4] = {bv.x, bv.y, bv.z, bv.w};
#pragma unroll
      for (int i = 0; i < 4; i++)
#pragma unroll
        for (int j = 0; j < 4; j++) acc[i][j] = fmaf(a[i], bb[j], acc[i][j]);
    }
  }

#pragma unroll
  for (int i = 0; i < 4; i++) {
    const int oG = ot * 64 + ty * 4 + i;
    const float sc = scale_bias[oG];
    const float bi = scale_bias[384 + oG];
    float4 r;
    r.x = fmaf(acc[i][0], sc, bi);
    r.y = fmaf(acc[i][1], sc, bi);
    r.z = fmaf(acc[i][2], sc, bi);
    r.w = fmaf(acc[i][3], sc, bi);
    *(float4*)&proj[((size_t)(b * 384 + oG)) * 4096 + nBase + tx * 4] = r;
  }
}

// ---------------------------------------------------------------------------
// Softmax (unchanged)
// ---------------------------------------------------------------------------
__global__ __launch_bounds__(256) void softmax_k(float* __restrict__ proj) {
  const int row = blockIdx.x;
  const int b = row >> 6, c = row & 63;
  float* p = proj + ((size_t)(b * 384 + 64 + c)) * 4096;
  const int tid = threadIdx.x;

  float4 v[4];
  float vmax = -3.4e38f;
#pragma unroll
  for (int i = 0; i < 4; i++) {
    v[i] = ((const float4*)p)[tid + i * 256];
    vmax = fmaxf(vmax, fmaxf(fmaxf(v[i].x, v[i].y), fmaxf(v[i].z, v[i].w)));
  }
#pragma unroll
  for (int off = 32; off > 0; off >>= 1) vmax = fmaxf(vmax, __shfl_xor(vmax, off));
  __shared__ float redm[4], reds[4];
  if ((tid & 63) == 0) redm[tid >> 6] = vmax;
  __syncthreads();
  vmax = fmaxf(fmaxf(redm[0], redm[1]), fmaxf(redm[2], redm[3]));

  float sum = 0.f;
#pragma unroll
  for (int i = 0; i < 4; i++) {
    v[i].x = expf(v[i].x - vmax); sum += v[i].x;
    v[i].y = expf(v[i].y - vmax); sum += v[i].y;
    v[i].z = expf(v[i].z - vmax); sum += v[i].z;
    v[i].w = expf(v[i].w - vmax); sum += v[i].w;
  }
#pragma unroll
  for (int off = 32; off > 0; off >>= 1) sum += __shfl_xor(sum, off);
  if ((tid & 63) == 0) reds[tid >> 6] = sum;
  __syncthreads();
  sum = reds[0] + reds[1] + reds[2] + reds[3];
  const float inv = 1.f / sum;
#pragma unroll
  for (int i = 0; i < 4; i++) {
    v[i].x *= inv; v[i].y *= inv; v[i].z *= inv; v[i].w *= inv;
    ((float4*)p)[tid + i * 256] = v[i];
  }
}

// ---------------------------------------------------------------------------
// Lc (unchanged)
// ---------------------------------------------------------------------------
__global__ __launch_bounds__(256) void lc_kernel(const float* __restrict__ proj,
                                                 float* __restrict__ Lc) {
  const int kk = blockIdx.x, b = blockIdx.y;
  const int tid = threadIdx.x;
  const int wave = tid >> 6, lane = tid & 63;
  float acc[16];
#pragma unroll
  for (int j = 0; j < 16; j++) acc[j] = 0.f;

  for (int u = 0; u < 4; u++) {
    const float* ks = proj + ((size_t)(b * 384 + 64 + u * 16 + kk)) * 4096;
    const float* vp = proj + ((size_t)(b * 384 + 128 + u * 64 + wave * 16)) * 4096;
    for (int m = lane; m < 4096; m += 64) {
      const float kvl = ks[m];
#pragma unroll
      for (int j = 0; j < 16; j++)
        acc[j] = fmaf(kvl, vp[(size_t)j * 4096 + m], acc[j]);
    }
  }
#pragma unroll
  for (int j = 0; j < 16; j++) {
#pragma unroll
    for (int off = 32; off > 0; off >>= 1) acc[j] += __shfl_xor(acc[j], off);
  }
  if (lane == 0) {
#pragma unroll
    for (int j = 0; j < 16; j++)
      Lc[(b * 16 + kk) * 64 + wave * 16 + j] = acc[j];
  }
}

// ---------------------------------------------------------------------------
// MFMA position-conv + Yp + Yc, transposed-image processing.
// Block = (dv, b, hf). LDS: vL[u][54 window-rows][88 cols] f16, pitch 88
// (2-way bank aliasing only). mfma 16x16x32_f16: m=kk, n=16 orig-cols,
// K=32 = one (transposed) kernel row, k-slide by off=gamma&7 so each
// B-fragment is one aligned ds_read_b128. A-fragments (23 per (u,off))
// held in VGPRs, loaded coalesced from prepacked global.
// ---------------------------------------------------------------------------
__global__ __launch_bounds__(256, 2) void lambda_conv(
    const float* __restrict__ proj, const _Float16* __restrict__ Apack,
    const float* __restrict__ Lc, const float* __restrict__ b_pos,
    float* __restrict__ out) {
  const int dv = blockIdx.x;
  const int b = blockIdx.y;
  const int hf = blockIdx.z;
  const int tid = threadIdx.x;
  const int w = tid >> 6;          // wave id: owns orig-rows [w*16, w*16+16)
  const int lane = tid & 63;
  const int quad = lane >> 4;
  const int n = lane & 15;

  __shared__ __align__(16) _Float16 vL[4 * 54 * 88];  // 38016 B

  // zero (covers halo)
  for (int i = tid; i < (4 * 54 * 88) / 2; i += 256) ((unsigned int*)vL)[i] = 0u;
  __syncthreads();

  // stage v (f32 -> f16), transposed: vL[u][lr = origcol - (hf*32-11)][origrow+11]
  {
    const float* vbase = proj + ((size_t)(b * 384 + 128 + dv)) * 4096;
    const int lr = lane + 11 - hf * 32;
    for (int t = w; t < 256; t += 4) {
      const int u = t >> 6, g = t & 63;  // g = orig row
      const float val = vbase[(size_t)u * 64 * 4096 + g * 64 + lane];
      if (lr >= 0 && lr < 54)
        vL[(u * 54 + lr) * 88 + g + 11] = (_Float16)val;
    }
  }
  __syncthreads();

  // Lc + b_pos per lane's 4 kk channels (kk = quad*4 + reg)
  float lcb[4];
#pragma unroll
  for (int reg = 0; reg < 4; reg++) {
    const int kk = quad * 4 + reg;
    lcb[reg] = Lc[(b * 16 + kk) * 64 + dv] + b_pos[kk];
  }

  const float* qbase = proj + ((size_t)(b * 384)) * 4096;

  for (int off = 0; off < 8; ++off) {
    f32x4 acc[2][2];
#pragma unroll
    for (int cc = 0; cc < 2; cc++)
#pragma unroll
      for (int rt = 0; rt < 2; rt++) acc[cc][rt] = (f32x4)0.f;

    for (int u = 0; u < 4; ++u) {
      // load A-set (u, off): 23 fragments, 92 VGPRs
      f16x8 A[23];
      const f16x8* ap = (const f16x8*)Apack + ((size_t)(off * 4 + u) * 23) * 64 + lane;
#pragma unroll
      for (int rp = 0; rp < 23; ++rp) A[rp] = ap[rp * 64];

      const _Float16* bb0 = &vL[(u * 54 + n) * 88 + w * 16 + quad * 8];
      const _Float16* bb1 = bb0 + 8;
#pragma unroll
      for (int sl = 0; sl < 39; ++sl) {
        const f16x8 B0 = *(const f16x8*)__builtin_assume_aligned(bb0 + sl * 88, 16);
        const f16x8 B1 = *(const f16x8*)__builtin_assume_aligned(bb1 + sl * 88, 16);
        if (sl < 23) {
          acc[0][0] = __builtin_amdgcn_mfma_f32_16x16x32_f16(A[sl], B0, acc[0][0], 0, 0, 0);
          acc[1][0] = __builtin_amdgcn_mfma_f32_16x16x32_f16(A[sl], B1, acc[1][0], 0, 0, 0);
        }
        if (sl >= 16) {
          acc[0][1] = __builtin_amdgcn_mfma_f32_16x16x32_f16(A[sl - 16], B0, acc[0][1], 0, 0, 0);
          acc[1][1] = __builtin_amdgcn_mfma_f32_16x16x32_f16(A[sl - 16], B1, acc[1][1], 0, 0, 0);
        }
      }
    }

    // epilogue for this off: 4 acc tiles -> Y
#pragma unroll
    for (int cc = 0; cc < 2; ++cc) {
      const int gamma = w * 16 + cc * 8 + off;  // orig row
#pragma unroll
      for (int rt = 0; rt < 2; ++rt) {
        const int ocol = hf * 32 + rt * 16 + n;  // orig col
        const float* qb = qbase + (size_t)gamma * 64 + ocol;
        float y0 = 0.f, y1 = 0.f, y2 = 0.f, y3 = 0.f;
#pragma unroll
        for (int reg = 0; reg < 4; reg++) {
          const float c = acc[cc][rt][reg] + lcb[reg];
          const int ch = quad * 4 + reg;
          y0 = fmaf(qb[(size_t)(ch) * 4096], c, y0);
          y1 = fmaf(qb[(size_t)(16 + ch) * 4096], c, y1);
          y2 = fmaf(qb[(size_t)(32 + ch) * 4096], c, y2);
          y3 = fmaf(qb[(size_t)(48 + ch) * 4096], c, y3);
        }
        y0 += __shfl_xor(y0, 16); y0 += __shfl_xor(y0, 32);
        y1 += __shfl_xor(y1, 16); y1 += __shfl_xor(y1, 32);
        y2 += __shfl_xor(y2, 16); y2 += __shfl_xor(y2, 32);
        y3 += __shfl_xor(y3, 16); y3 += __shfl_xor(y3, 32);
        const float yo = (quad == 0) ? y0 : (quad == 1) ? y1 : (quad == 2) ? y2 : y3;
        out[((size_t)(b * 256 + quad * 64 + dv)) * 4096 + gamma * 64 + ocol] = yo;
      }
    }
  }
}

// ---------------------------------------------------------------------------
extern "C" void kernel_launch(void* const* d_in, const int* in_sizes, int n_in,
                              void* d_out, int out_size, void* d_ws, size_t ws_size,
                              hipStream_t stream) {
  const float* x       = (const float*)d_in[0];
  const float* w_q     = (const float*)d_in[1];
  const float* w_k     = (const float*)d_in[2];
  const float* w_v     = (const float*)d_in[3];
  const float* gamma_q = (const float*)d_in[4];
  const float* beta_q  = (const float*)d_in[5];
  const float* mean_q  = (const float*)d_in[6];
  const float* var_q   = (const float*)d_in[7];
  const float* gamma_v = (const float*)d_in[8];
  const float* beta_v  = (const float*)d_in[9];
  const float* mean_v  = (const float*)d_in[10];
  const float* var_v   = (const float*)d_in[11];
  const float* w_pos   = (const float*)d_in[12];
  const float* b_pos   = (const float*)d_in[13];

  float* ws = (float*)d_ws;
  float* proj = ws;                            // 16*384*4096 = 25165824 floats
  float* sb   = ws + 25165824;                 // 768 floats
  float* Lc   = sb + 768;                      // 16384 floats
  _Float16* Apack = (_Float16*)(Lc + 16384);   // 376832 halfs (16B-aligned)
  float* out = (float*)d_out;

  setup_kernel<<<1472, 256, 0, stream>>>(w_pos, gamma_q, beta_q, mean_q, var_q,
                                         gamma_v, beta_v, mean_v, var_v, sb, Apack);
  proj_gemm<<<dim3(64, 6, 16), 256, 0, stream>>>(x, w_q, w_k, w_v, sb, proj);
  softmax_k<<<1024, 256, 0, stream>>>(proj);
  lc_kernel<<<dim3(16, 16), 256, 0, stream>>>(proj, Lc);
  lambda_conv<<<dim3(64, 16, 2), 256, 0, stream>>>(proj, Apack, Lc, b_pos, out);
}

// Round 3
// 941.837 us; speedup vs baseline: 6.8364x; 6.8364x over previous
//
#include <hip/hip_runtime.h>
#include <stdint.h>

#define EPS 1e-3f

typedef _Float16 f16x8 __attribute__((ext_vector_type(8)));
typedef float f32x4 __attribute__((ext_vector_type(4)));

// ---------------------------------------------------------------------------
// Setup: fold BN into per-channel scale/bias; prepack w_pos into 8 "slide"
// variants of MFMA A-fragments (f16), transposed taps (r<->s):
//   Apack[off][u][rp][lane][j] = w_pos[kk=lane&15][u][sp=(lane>>4)*8+j-off][rp]
//   (zero when sp outside [0,23))
// ---------------------------------------------------------------------------
__global__ __launch_bounds__(256) void setup_kernel(
    const float* __restrict__ w_pos,
    const float* __restrict__ gq, const float* __restrict__ bq,
    const float* __restrict__ mq, const float* __restrict__ vq,
    const float* __restrict__ gv, const float* __restrict__ bv,
    const float* __restrict__ mv, const float* __restrict__ vvar,
    float* __restrict__ scale_bias, _Float16* __restrict__ Apack) {
  const int idx = blockIdx.x * 256 + threadIdx.x;
  if (idx < 384) {
    float sc, bi;
    if (idx < 64) {
      const float inv = gq[idx] * rsqrtf(vq[idx] + EPS);
      sc = inv; bi = bq[idx] - mq[idx] * inv;
    } else if (idx < 128) {
      sc = 1.f; bi = 0.f;  // k has no BN
    } else {
      const int o = idx - 128;
      const float inv = gv[o] * rsqrtf(vvar[o] + EPS);
      sc = inv; bi = bv[o] - mv[o] * inv;
    }
    scale_bias[idx] = sc;
    scale_bias[384 + idx] = bi;
  }
  if (idx < 376832) {  // 8 off * 4 u * 23 rp * 64 lanes * 8 halfs
    const int j = idx & 7;
    const int lane = (idx >> 3) & 63;
    const int rp = (idx >> 9) % 23;
    const int uo = (idx >> 9) / 23;
    const int u = uo & 3;
    const int off = uo >> 2;
    const int kk = lane & 15;
    const int quad = (lane >> 4) & 3;
    const int sp = quad * 8 + j - off;  // dy index
    float val = 0.f;
    if (sp >= 0 && sp < 23)
      val = w_pos[kk * 2116 + u * 529 + sp * 23 + rp];
    Apack[idx] = (_Float16)val;
  }
}

// ---------------------------------------------------------------------------
// Projection GEMM (unchanged)
// ---------------------------------------------------------------------------
__global__ __launch_bounds__(256) void proj_gemm(
    const float* __restrict__ x,
    const float* __restrict__ w_q, const float* __restrict__ w_k,
    const float* __restrict__ w_v,
    const float* __restrict__ scale_bias,
    float* __restrict__ proj) {
  const int b = blockIdx.z;
  const int ot = blockIdx.y;
  const int nBase = blockIdx.x * 64;
  const int tid = threadIdx.x;
  const int tx = tid & 15, ty = tid >> 4;

  const float* W;
  int oRow;
  if (ot == 0)      { W = w_q; oRow = 0; }
  else if (ot == 1) { W = w_k; oRow = 0; }
  else              { W = w_v; oRow = (ot - 2) * 64; }

  __shared__ float la[32][64];
  __shared__ float lb[32][64];

  float acc[4][4];
#pragma unroll
  for (int i = 0; i < 4; i++)
#pragma unroll
    for (int j = 0; j < 4; j++) acc[i][j] = 0.f;

  const int o_l = tid & 63;
  const int c4a = (tid >> 6) * 4;
  const int cb = tid >> 4;
  const int n4 = (tid & 15) * 4;

  for (int k0 = 0; k0 < 256; k0 += 32) {
    __syncthreads();
#pragma unroll
    for (int rr = 0; rr < 2; rr++) {
      const int c0 = c4a + rr * 16;
      const float4 wv4 = *(const float4*)&W[(size_t)(oRow + o_l) * 256 + k0 + c0];
      la[c0 + 0][o_l] = wv4.x;
      la[c0 + 1][o_l] = wv4.y;
      la[c0 + 2][o_l] = wv4.z;
      la[c0 + 3][o_l] = wv4.w;
    }
#pragma unroll
    for (int rr = 0; rr < 2; rr++) {
      const int c_l = cb + rr * 16;
      const float4 xv =
          *(const float4*)&x[((size_t)(b * 256 + k0 + c_l)) * 4096 + nBase + n4];
      *(float4*)&lb[c_l][n4] = xv;
    }
    __syncthreads();
#pragma unroll
    for (int kk = 0; kk < 32; kk++) {
      const float4 av = *(const float4*)&la[kk][ty * 4];
      const float4 bv = *(const float4*)&lb[kk][tx * 4];
      const float a[4] = {av.x, av.y, av.z, av.w};
      const float bb[4] = {bv.x, bv.y, bv.z, bv.w};
#pragma unroll
      for (int i = 0; i < 4; i++)
#pragma unroll
        for (int j = 0; j < 4; j++) acc[i][j] = fmaf(a[i], bb[j], acc[i][j]);
    }
  }

#pragma unroll
  for (int i = 0; i < 4; i++) {
    const int oG = ot * 64 + ty * 4 + i;
    const float sc = scale_bias[oG];
    const float bi = scale_bias[384 + oG];
    float4 r;
    r.x = fmaf(acc[i][0], sc, bi);
    r.y = fmaf(acc[i][1], sc, bi);
    r.z = fmaf(acc[i][2], sc, bi);
    r.w = fmaf(acc[i][3], sc, bi);
    *(float4*)&proj[((size_t)(b * 384 + oG)) * 4096 + nBase + tx * 4] = r;
  }
}

// ---------------------------------------------------------------------------
// Softmax (unchanged)
// ---------------------------------------------------------------------------
__global__ __launch_bounds__(256) void softmax_k(float* __restrict__ proj) {
  const int row = blockIdx.x;
  const int b = row >> 6, c = row & 63;
  float* p = proj + ((size_t)(b * 384 + 64 + c)) * 4096;
  const int tid = threadIdx.x;

  float4 v[4];
  float vmax = -3.4e38f;
#pragma unroll
  for (int i = 0; i < 4; i++) {
    v[i] = ((const float4*)p)[tid + i * 256];
    vmax = fmaxf(vmax, fmaxf(fmaxf(v[i].x, v[i].y), fmaxf(v[i].z, v[i].w)));
  }
#pragma unroll
  for (int off = 32; off > 0; off >>= 1) vmax = fmaxf(vmax, __shfl_xor(vmax, off));
  __shared__ float redm[4], reds[4];
  if ((tid & 63) == 0) redm[tid >> 6] = vmax;
  __syncthreads();
  vmax = fmaxf(fmaxf(redm[0], redm[1]), fmaxf(redm[2], redm[3]));

  float sum = 0.f;
#pragma unroll
  for (int i = 0; i < 4; i++) {
    v[i].x = expf(v[i].x - vmax); sum += v[i].x;
    v[i].y = expf(v[i].y - vmax); sum += v[i].y;
    v[i].z = expf(v[i].z - vmax); sum += v[i].z;
    v[i].w = expf(v[i].w - vmax); sum += v[i].w;
  }
#pragma unroll
  for (int off = 32; off > 0; off >>= 1) sum += __shfl_xor(sum, off);
  if ((tid & 63) == 0) reds[tid >> 6] = sum;
  __syncthreads();
  sum = reds[0] + reds[1] + reds[2] + reds[3];
  const float inv = 1.f / sum;
#pragma unroll
  for (int i = 0; i < 4; i++) {
    v[i].x *= inv; v[i].y *= inv; v[i].z *= inv; v[i].w *= inv;
    ((float4*)p)[tid + i * 256] = v[i];
  }
}

// ---------------------------------------------------------------------------
// Lc (unchanged)
// ---------------------------------------------------------------------------
__global__ __launch_bounds__(256) void lc_kernel(const float* __restrict__ proj,
                                                 float* __restrict__ Lc) {
  const int kk = blockIdx.x, b = blockIdx.y;
  const int tid = threadIdx.x;
  const int wave = tid >> 6, lane = tid & 63;
  float acc[16];
#pragma unroll
  for (int j = 0; j < 16; j++) acc[j] = 0.f;

  for (int u = 0; u < 4; u++) {
    const float* ks = proj + ((size_t)(b * 384 + 64 + u * 16 + kk)) * 4096;
    const float* vp = proj + ((size_t)(b * 384 + 128 + u * 64 + wave * 16)) * 4096;
    for (int m = lane; m < 4096; m += 64) {
      const float kvl = ks[m];
#pragma unroll
      for (int j = 0; j < 16; j++)
        acc[j] = fmaf(kvl, vp[(size_t)j * 4096 + m], acc[j]);
    }
  }
#pragma unroll
  for (int j = 0; j < 16; j++) {
#pragma unroll
    for (int off = 32; off > 0; off >>= 1) acc[j] += __shfl_xor(acc[j], off);
  }
  if (lane == 0) {
#pragma unroll
    for (int j = 0; j < 16; j++)
      Lc[(b * 16 + kk) * 64 + wave * 16 + j] = acc[j];
  }
}

// ---------------------------------------------------------------------------
// MFMA position-conv + Yp + Yc. Block = (dv, b): full 64x64 image.
// LDS: vL[u][c+11 (86)][g+11 (88)] f16 (transposed image, zero halo).
// Wave w handles off in {2w, 2w+1}: gammas = 8t+off. Per (off,pass):
// acc[t=8][rt=2], A (23 frags) reloaded per u from L2-resident Apack.
// Epilogue: q-contraction + LDS bounce -> two 128B-line nt-stores per tile.
// ---------------------------------------------------------------------------
__global__ __launch_bounds__(256, 2) void lambda_conv(
    const float* __restrict__ proj, const _Float16* __restrict__ Apack,
    const float* __restrict__ Lc, const float* __restrict__ b_pos,
    float* __restrict__ out) {
  const int dv = blockIdx.x;
  const int b = blockIdx.y;
  const int tid = threadIdx.x;
  const int w = tid >> 6;
  const int lane = tid & 63;
  const int q = lane >> 4;
  const int n = lane & 15;

  __shared__ __align__(16) _Float16 vL[4 * 86 * 88];  // 60544 B
  __shared__ float scr[4][128];                        // 2 KB bounce

  // zero LDS (halo)
  for (int i = tid; i < (4 * 86 * 88) / 2; i += 256) ((unsigned int*)vL)[i] = 0u;
  __syncthreads();

  // stage v (f32 -> f16), transposed: vL[u][c+11][g+11]
  {
    const float* vsec = proj + ((size_t)(b * 384 + 128 + dv)) * 4096;
    for (int idx = tid; idx < 4096; idx += 256) {
      const int u = idx >> 10, g = (idx >> 4) & 63, c4 = (idx & 15) * 4;
      const float4 vv = *(const float4*)&vsec[(size_t)u * 64 * 4096 + g * 64 + c4];
      vL[(u * 86 + c4 + 11) * 88 + g + 11] = (_Float16)vv.x;
      vL[(u * 86 + c4 + 12) * 88 + g + 11] = (_Float16)vv.y;
      vL[(u * 86 + c4 + 13) * 88 + g + 11] = (_Float16)vv.z;
      vL[(u * 86 + c4 + 14) * 88 + g + 11] = (_Float16)vv.w;
    }
  }
  __syncthreads();

  float lcb[4];
#pragma unroll
  for (int reg = 0; reg < 4; reg++) {
    const int kk = q * 4 + reg;
    lcb[reg] = Lc[(b * 16 + kk) * 64 + dv] + b_pos[kk];
  }

  const float* qsec = proj + ((size_t)(b * 384)) * 4096;

#pragma unroll 1
  for (int op = 0; op < 2; ++op) {
    const int off = w * 2 + op;
#pragma unroll 1
    for (int pass = 0; pass < 2; ++pass) {
      f32x4 acc[8][2];
#pragma unroll
      for (int t = 0; t < 8; t++)
#pragma unroll
        for (int rt = 0; rt < 2; rt++) acc[t][rt] = (f32x4)0.f;

#pragma unroll 1
      for (int u = 0; u < 4; ++u) {
        f16x8 A[23];
        const f16x8* ap =
            (const f16x8*)Apack + ((size_t)(off * 4 + u) * 23) * 64 + lane;
#pragma unroll
        for (int rp = 0; rp < 23; ++rp) A[rp] = ap[rp * 64];

        const _Float16* bbase = &vL[(u * 86 + 32 * pass + n) * 88 + 8 * q];
#pragma unroll
        for (int t = 0; t < 8; ++t) {
          const _Float16* bt = bbase + 8 * t;
#pragma unroll
          for (int ss = 0; ss < 39; ++ss) {
            const f16x8 B =
                *(const f16x8*)__builtin_assume_aligned(bt + ss * 88, 16);
            if (ss < 23)
              acc[t][0] =
                  __builtin_amdgcn_mfma_f32_16x16x32_f16(A[ss], B, acc[t][0], 0, 0, 0);
            if (ss >= 16)
              acc[t][1] = __builtin_amdgcn_mfma_f32_16x16x32_f16(A[ss - 16], B,
                                                                 acc[t][1], 0, 0, 0);
          }
        }
      }

      // epilogue for (off, pass)
#pragma unroll 1
      for (int t = 0; t < 8; ++t) {
        const int gamma = 8 * t + off;
#pragma unroll
        for (int rt = 0; rt < 2; ++rt) {
          const int c = 32 * pass + 16 * rt + n;
          const float* qp = qsec + (size_t)gamma * 64 + c;
          float y0 = 0.f, y1 = 0.f, y2 = 0.f, y3 = 0.f;
#pragma unroll
          for (int reg = 0; reg < 4; reg++) {
            const float cf = acc[t][rt][reg] + lcb[reg];
            const int ch = q * 4 + reg;
            y0 = fmaf(qp[(size_t)(ch) * 4096], cf, y0);
            y1 = fmaf(qp[(size_t)(16 + ch) * 4096], cf, y1);
            y2 = fmaf(qp[(size_t)(32 + ch) * 4096], cf, y2);
            y3 = fmaf(qp[(size_t)(48 + ch) * 4096], cf, y3);
          }
          y0 += __shfl_xor(y0, 16); y0 += __shfl_xor(y0, 32);
          y1 += __shfl_xor(y1, 16); y1 += __shfl_xor(y1, 32);
          y2 += __shfl_xor(y2, 16); y2 += __shfl_xor(y2, 32);
          y3 += __shfl_xor(y3, 16); y3 += __shfl_xor(y3, 32);
          const float yo = (q == 0) ? y0 : (q == 1) ? y1 : (q == 2) ? y2 : y3;
          scr[w][q * 32 + 16 * rt + n] = yo;
        }
        __asm__ volatile("s_waitcnt lgkmcnt(0)");
        const float e0 = scr[w][lane];
        const float e1 = scr[w][64 + lane];
        const int h0 = lane >> 5, cl = lane & 31;
        float* o0 =
            &out[((size_t)(b * 256 + h0 * 64 + dv)) * 4096 + gamma * 64 + 32 * pass + cl];
        float* o1 =
            &out[((size_t)(b * 256 + (2 + h0) * 64 + dv)) * 4096 + gamma * 64 + 32 * pass + cl];
        __builtin_nontemporal_store(e0, o0);
        __builtin_nontemporal_store(e1, o1);
        __asm__ volatile("s_waitcnt lgkmcnt(0)");
      }
    }
  }
}

// ---------------------------------------------------------------------------
extern "C" void kernel_launch(void* const* d_in, const int* in_sizes, int n_in,
                              void* d_out, int out_size, void* d_ws, size_t ws_size,
                              hipStream_t stream) {
  const float* x       = (const float*)d_in[0];
  const float* w_q     = (const float*)d_in[1];
  const float* w_k     = (const float*)d_in[2];
  const float* w_v     = (const float*)d_in[3];
  const float* gamma_q = (const float*)d_in[4];
  const float* beta_q  = (const float*)d_in[5];
  const float* mean_q  = (const float*)d_in[6];
  const float* var_q   = (const float*)d_in[7];
  const float* gamma_v = (const float*)d_in[8];
  const float* beta_v  = (const float*)d_in[9];
  const float* mean_v  = (const float*)d_in[10];
  const float* var_v   = (const float*)d_in[11];
  const float* w_pos   = (const float*)d_in[12];
  const float* b_pos   = (const float*)d_in[13];

  float* ws = (float*)d_ws;
  float* proj = ws;                            // 16*384*4096 floats
  float* sb   = ws + 25165824;                 // 768 floats
  float* Lc   = sb + 768;                      // 16384 floats
  _Float16* Apack = (_Float16*)(Lc + 16384);   // 376832 halfs
  float* out = (float*)d_out;

  setup_kernel<<<1472, 256, 0, stream>>>(w_pos, gamma_q, beta_q, mean_q, var_q,
                                         gamma_v, beta_v, mean_v, var_v, sb, Apack);
  proj_gemm<<<dim3(64, 6, 16), 256, 0, stream>>>(x, w_q, w_k, w_v, sb, proj);
  softmax_k<<<1024, 256, 0, stream>>>(proj);
  lc_kernel<<<dim3(16, 16), 256, 0, stream>>>(proj, Lc);
  lambda_conv<<<dim3(64, 16), 256, 0, stream>>>(proj, Apack, Lc, b_pos, out);
}

// Round 4
// 834.928 us; speedup vs baseline: 7.7118x; 1.1280x over previous
//
#include <hip/hip_runtime.h>
#include <stdint.h>

#define EPS 1e-3f

typedef _Float16 f16x8 __attribute__((ext_vector_type(8)));
typedef float f32x4 __attribute__((ext_vector_type(4)));
typedef float f32x16 __attribute__((ext_vector_type(16)));

// ---------------------------------------------------------------------------
// Setup: fold BN into scale/bias; prepack w_pos into 32x32x16-MFMA A-frags:
//   m = ol*16+kk (ol = off&1 batched pair, off = 2w+ol), k = (lane>>5)*8+j,
//   frag f = ((w*4+u)*23+ss)*2 + d  (d: delta' = 2d window selector)
//   value = w_pos[kk][u][dy = 16d + k - 2w - ol][ss]  (0 if dy outside [0,23))
// ---------------------------------------------------------------------------
__global__ __launch_bounds__(256) void setup_kernel(
    const float* __restrict__ w_pos,
    const float* __restrict__ gq, const float* __restrict__ bq,
    const float* __restrict__ mq, const float* __restrict__ vq,
    const float* __restrict__ gv, const float* __restrict__ bv,
    const float* __restrict__ mv, const float* __restrict__ vvar,
    float* __restrict__ scale_bias, _Float16* __restrict__ Apack) {
  const int idx = blockIdx.x * 256 + threadIdx.x;
  if (idx < 384) {
    float sc, bi;
    if (idx < 64) {
      const float inv = gq[idx] * rsqrtf(vq[idx] + EPS);
      sc = inv; bi = bq[idx] - mq[idx] * inv;
    } else if (idx < 128) {
      sc = 1.f; bi = 0.f;  // k has no BN
    } else {
      const int o = idx - 128;
      const float inv = gv[o] * rsqrtf(vvar[o] + EPS);
      sc = inv; bi = bv[o] - mv[o] * inv;
    }
    scale_bias[idx] = sc;
    scale_bias[384 + idx] = bi;
  }
  if (idx < 376832) {  // 736 frags * 64 lanes * 8 halfs
    const int j = idx & 7;
    const int lane = (idx >> 3) & 63;
    const int f = idx >> 9;
    const int d = f & 1;
    const int ss = (f >> 1) % 23;
    const int uw = (f >> 1) / 23;
    const int u = uw & 3;
    const int w = uw >> 2;
    const int m = lane & 31;
    const int kap = lane >> 5;
    const int kk = m & 15;
    const int ol = m >> 4;
    const int k = kap * 8 + j;
    const int dy = 16 * d + k - 2 * w - ol;
    float val = 0.f;
    if (dy >= 0 && dy < 23)
      val = w_pos[kk * 2116 + u * 529 + dy * 23 + ss];
    Apack[idx] = (_Float16)val;
  }
}

// ---------------------------------------------------------------------------
// Projection GEMM (unchanged)
// ---------------------------------------------------------------------------
__global__ __launch_bounds__(256) void proj_gemm(
    const float* __restrict__ x,
    const float* __restrict__ w_q, const float* __restrict__ w_k,
    const float* __restrict__ w_v,
    const float* __restrict__ scale_bias,
    float* __restrict__ proj) {
  const int b = blockIdx.z;
  const int ot = blockIdx.y;
  const int nBase = blockIdx.x * 64;
  const int tid = threadIdx.x;
  const int tx = tid & 15, ty = tid >> 4;

  const float* W;
  int oRow;
  if (ot == 0)      { W = w_q; oRow = 0; }
  else if (ot == 1) { W = w_k; oRow = 0; }
  else              { W = w_v; oRow = (ot - 2) * 64; }

  __shared__ float la[32][64];
  __shared__ float lb[32][64];

  float acc[4][4];
#pragma unroll
  for (int i = 0; i < 4; i++)
#pragma unroll
    for (int j = 0; j < 4; j++) acc[i][j] = 0.f;

  const int o_l = tid & 63;
  const int c4a = (tid >> 6) * 4;
  const int cb = tid >> 4;
  const int n4 = (tid & 15) * 4;

  for (int k0 = 0; k0 < 256; k0 += 32) {
    __syncthreads();
#pragma unroll
    for (int rr = 0; rr < 2; rr++) {
      const int c0 = c4a + rr * 16;
      const float4 wv4 = *(const float4*)&W[(size_t)(oRow + o_l) * 256 + k0 + c0];
      la[c0 + 0][o_l] = wv4.x;
      la[c0 + 1][o_l] = wv4.y;
      la[c0 + 2][o_l] = wv4.z;
      la[c0 + 3][o_l] = wv4.w;
    }
#pragma unroll
    for (int rr = 0; rr < 2; rr++) {
      const int c_l = cb + rr * 16;
      const float4 xv =
          *(const float4*)&x[((size_t)(b * 256 + k0 + c_l)) * 4096 + nBase + n4];
      *(float4*)&lb[c_l][n4] = xv;
    }
    __syncthreads();
#pragma unroll
    for (int kk = 0; kk < 32; kk++) {
      const float4 av = *(const float4*)&la[kk][ty * 4];
      const float4 bv = *(const float4*)&lb[kk][tx * 4];
      const float a[4] = {av.x, av.y, av.z, av.w};
      const float bb[4] = {bv.x, bv.y, bv.z, bv.w};
#pragma unroll
      for (int i = 0; i < 4; i++)
#pragma unroll
        for (int j = 0; j < 4; j++) acc[i][j] = fmaf(a[i], bb[j], acc[i][j]);
    }
  }

#pragma unroll
  for (int i = 0; i < 4; i++) {
    const int oG = ot * 64 + ty * 4 + i;
    const float sc = scale_bias[oG];
    const float bi = scale_bias[384 + oG];
    float4 r;
    r.x = fmaf(acc[i][0], sc, bi);
    r.y = fmaf(acc[i][1], sc, bi);
    r.z = fmaf(acc[i][2], sc, bi);
    r.w = fmaf(acc[i][3], sc, bi);
    *(float4*)&proj[((size_t)(b * 384 + oG)) * 4096 + nBase + tx * 4] = r;
  }
}

// ---------------------------------------------------------------------------
// Softmax (unchanged)
// ---------------------------------------------------------------------------
__global__ __launch_bounds__(256) void softmax_k(float* __restrict__ proj) {
  const int row = blockIdx.x;
  const int b = row >> 6, c = row & 63;
  float* p = proj + ((size_t)(b * 384 + 64 + c)) * 4096;
  const int tid = threadIdx.x;

  float4 v[4];
  float vmax = -3.4e38f;
#pragma unroll
  for (int i = 0; i < 4; i++) {
    v[i] = ((const float4*)p)[tid + i * 256];
    vmax = fmaxf(vmax, fmaxf(fmaxf(v[i].x, v[i].y), fmaxf(v[i].z, v[i].w)));
  }
#pragma unroll
  for (int off = 32; off > 0; off >>= 1) vmax = fmaxf(vmax, __shfl_xor(vmax, off));
  __shared__ float redm[4], reds[4];
  if ((tid & 63) == 0) redm[tid >> 6] = vmax;
  __syncthreads();
  vmax = fmaxf(fmaxf(redm[0], redm[1]), fmaxf(redm[2], redm[3]));

  float sum = 0.f;
#pragma unroll
  for (int i = 0; i < 4; i++) {
    v[i].x = expf(v[i].x - vmax); sum += v[i].x;
    v[i].y = expf(v[i].y - vmax); sum += v[i].y;
    v[i].z = expf(v[i].z - vmax); sum += v[i].z;
    v[i].w = expf(v[i].w - vmax); sum += v[i].w;
  }
#pragma unroll
  for (int off = 32; off > 0; off >>= 1) sum += __shfl_xor(sum, off);
  if ((tid & 63) == 0) reds[tid >> 6] = sum;
  __syncthreads();
  sum = reds[0] + reds[1] + reds[2] + reds[3];
  const float inv = 1.f / sum;
#pragma unroll
  for (int i = 0; i < 4; i++) {
    v[i].x *= inv; v[i].y *= inv; v[i].z *= inv; v[i].w *= inv;
    ((float4*)p)[tid + i * 256] = v[i];
  }
}

// ---------------------------------------------------------------------------
// Lc (unchanged)
// ---------------------------------------------------------------------------
__global__ __launch_bounds__(256) void lc_kernel(const float* __restrict__ proj,
                                                 float* __restrict__ Lc) {
  const int kk = blockIdx.x, b = blockIdx.y;
  const int tid = threadIdx.x;
  const int wave = tid >> 6, lane = tid & 63;
  float acc[16];
#pragma unroll
  for (int j = 0; j < 16; j++) acc[j] = 0.f;

  for (int u = 0; u < 4; u++) {
    const float* ks = proj + ((size_t)(b * 384 + 64 + u * 16 + kk)) * 4096;
    const float* vp = proj + ((size_t)(b * 384 + 128 + u * 64 + wave * 16)) * 4096;
    for (int m = lane; m < 4096; m += 64) {
      const float kvl = ks[m];
#pragma unroll
      for (int j = 0; j < 16; j++)
        acc[j] = fmaf(kvl, vp[(size_t)j * 4096 + m], acc[j]);
    }
  }
#pragma unroll
  for (int j = 0; j < 16; j++) {
#pragma unroll
    for (int off = 32; off > 0; off >>= 1) acc[j] += __shfl_xor(acc[j], off);
  }
  if (lane == 0) {
#pragma unroll
    for (int j = 0; j < 16; j++)
      Lc[(b * 16 + kk) * 64 + wave * 16 + j] = acc[j];
  }
}

// ---------------------------------------------------------------------------
// MFMA position-conv + Yp + Yc. Block = (dv, b). 32x32x16_f16:
//   m = ol*16+kk (off = 2w+ol batched in m), n = 32 output cols, K=16 g-octets.
// Per (u,pass,ss): 10 ds_read_b128 (windows tau=0..9) feed 16 MFMAs
// (t=0..7, windows tau=t and tau=t+2; A gives tap row ss, shifted dy).
// Epilogue: q-contraction per lane (8 kk), kappa-pair shfl reduce, direct
// coalesced 128B-line stores (no nt, no LDS bounce).
// ---------------------------------------------------------------------------
__global__ __launch_bounds__(256, 2) void lambda_conv(
    const float* __restrict__ proj, const _Float16* __restrict__ Apack,
    const float* __restrict__ Lc, const float* __restrict__ b_pos,
    float* __restrict__ out) {
  const int dv = blockIdx.x;
  const int b = blockIdx.y;
  const int tid = threadIdx.x;
  const int w = tid >> 6;          // wave: off pair {2w, 2w+1}
  const int lane = tid & 63;
  const int n = lane & 31;         // output col within pass
  const int kap = lane >> 5;

  __shared__ __align__(16) _Float16 vL[4 * 86 * 88];  // 60544 B

  // zero LDS (halo)
  for (int i = tid; i < (4 * 86 * 88) / 2; i += 256) ((unsigned int*)vL)[i] = 0u;
  __syncthreads();

  // stage v (f32 -> f16), transposed: vL[u][c+11][g+11]
  {
    const float* vsec = proj + ((size_t)(b * 384 + 128 + dv)) * 4096;
    for (int idx = tid; idx < 4096; idx += 256) {
      const int u = idx >> 10, g = (idx >> 4) & 63, c4 = (idx & 15) * 4;
      const float4 vv = *(const float4*)&vsec[(size_t)u * 64 * 4096 + g * 64 + c4];
      vL[(u * 86 + c4 + 11) * 88 + g + 11] = (_Float16)vv.x;
      vL[(u * 86 + c4 + 12) * 88 + g + 11] = (_Float16)vv.y;
      vL[(u * 86 + c4 + 13) * 88 + g + 11] = (_Float16)vv.z;
      vL[(u * 86 + c4 + 14) * 88 + g + 11] = (_Float16)vv.w;
    }
  }
  __syncthreads();

  // Lc + b_pos for this lane's 8 kk channels: kk_e = (e&3) + 8*(e>>2) + 4*kap
  float lcb[8];
#pragma unroll
  for (int e = 0; e < 8; e++) {
    const int kk = (e & 3) + 8 * (e >> 2) + 4 * kap;
    lcb[e] = Lc[(b * 16 + kk) * 64 + dv] + b_pos[kk];
  }

  const float* qsec = proj + ((size_t)(b * 384)) * 4096;
  const f16x8* Ap = (const f16x8*)Apack;

#pragma unroll 1
  for (int pass = 0; pass < 2; ++pass) {
    f32x16 acc[8];
#pragma unroll
    for (int t = 0; t < 8; t++) acc[t] = (f32x16)0.f;

#pragma unroll 1
    for (int u = 0; u < 4; ++u) {
      const f16x8* Ab = Ap + (size_t)((w * 4 + u) * 23) * 2 * 64 + lane;
      f16x8 A0 = Ab[0];
      f16x8 A1 = Ab[64];
#pragma unroll 1
      for (int ss = 0; ss < 23; ++ss) {
        const int ssn = (ss < 22) ? ss + 1 : 22;
        const f16x8 A0n = Ab[ssn * 128];
        const f16x8 A1n = Ab[ssn * 128 + 64];

        const _Float16* brow = &vL[(u * 86 + 32 * pass + n + ss) * 88 + 8 * kap];
        f16x8 B[10];
#pragma unroll
        for (int tau = 0; tau < 10; ++tau)
          B[tau] = *(const f16x8*)__builtin_assume_aligned(brow + 8 * tau, 16);

#pragma unroll
        for (int t = 0; t < 8; ++t) {
          acc[t] = __builtin_amdgcn_mfma_f32_32x32x16_f16(A0, B[t], acc[t], 0, 0, 0);
          acc[t] = __builtin_amdgcn_mfma_f32_32x32x16_f16(A1, B[t + 2], acc[t], 0, 0, 0);
        }
        A0 = A0n;
        A1 = A1n;
      }
    }

    // epilogue: for each (t, ol): gamma = 8t + 2w + ol
    const int c = 32 * pass + n;
#pragma unroll 1
    for (int t = 0; t < 8; ++t) {
#pragma unroll
      for (int ol = 0; ol < 2; ++ol) {
        const int gamma = 8 * t + 2 * w + ol;
        const float* qg = qsec + (size_t)gamma * 64 + c;
        float y0 = 0.f, y1 = 0.f, y2 = 0.f, y3 = 0.f;
#pragma unroll
        for (int e = 0; e < 8; ++e) {
          const int kk = (e & 3) + 8 * (e >> 2) + 4 * kap;
          const float cf = acc[t][ol * 8 + e] + lcb[e];
          y0 = fmaf(qg[(size_t)(kk) * 4096], cf, y0);
          y1 = fmaf(qg[(size_t)(16 + kk) * 4096], cf, y1);
          y2 = fmaf(qg[(size_t)(32 + kk) * 4096], cf, y2);
          y3 = fmaf(qg[(size_t)(48 + kk) * 4096], cf, y3);
        }
        y0 += __shfl_xor(y0, 32);
        y1 += __shfl_xor(y1, 32);
        y2 += __shfl_xor(y2, 32);
        y3 += __shfl_xor(y3, 32);
        const float s0 = kap ? y2 : y0;  // h = 2*kap
        const float s1 = kap ? y3 : y1;  // h = 2*kap + 1
        out[((size_t)(b * 256 + (2 * kap + 0) * 64 + dv)) * 4096 + gamma * 64 + c] = s0;
        out[((size_t)(b * 256 + (2 * kap + 1) * 64 + dv)) * 4096 + gamma * 64 + c] = s1;
      }
    }
  }
}

// ---------------------------------------------------------------------------
extern "C" void kernel_launch(void* const* d_in, const int* in_sizes, int n_in,
                              void* d_out, int out_size, void* d_ws, size_t ws_size,
                              hipStream_t stream) {
  const float* x       = (const float*)d_in[0];
  const float* w_q     = (const float*)d_in[1];
  const float* w_k     = (const float*)d_in[2];
  const float* w_v     = (const float*)d_in[3];
  const float* gamma_q = (const float*)d_in[4];
  const float* beta_q  = (const float*)d_in[5];
  const float* mean_q  = (const float*)d_in[6];
  const float* var_q   = (const float*)d_in[7];
  const float* gamma_v = (const float*)d_in[8];
  const float* beta_v  = (const float*)d_in[9];
  const float* mean_v  = (const float*)d_in[10];
  const float* var_v   = (const float*)d_in[11];
  const float* w_pos   = (const float*)d_in[12];
  const float* b_pos   = (const float*)d_in[13];

  float* ws = (float*)d_ws;
  float* proj = ws;                            // 16*384*4096 floats
  float* sb   = ws + 25165824;                 // 768 floats
  float* Lc   = sb + 768;                      // 16384 floats
  _Float16* Apack = (_Float16*)(Lc + 16384);   // 376832 halfs
  float* out = (float*)d_out;

  setup_kernel<<<1472, 256, 0, stream>>>(w_pos, gamma_q, beta_q, mean_q, var_q,
                                         gamma_v, beta_v, mean_v, var_v, sb, Apack);
  proj_gemm<<<dim3(64, 6, 16), 256, 0, stream>>>(x, w_q, w_k, w_v, sb, proj);
  softmax_k<<<1024, 256, 0, stream>>>(proj);
  lc_kernel<<<dim3(16, 16), 256, 0, stream>>>(proj, Lc);
  lambda_conv<<<dim3(64, 16), 256, 0, stream>>>(proj, Apack, Lc, b_pos, out);
}